// Round 3
// baseline (103.442 us; speedup 1.0000x reference)
//
#include <hip/hip_runtime.h>
#include <math.h>

// B=256, K=51, N=8192. out = MULT * sum_{b,d} sqrt(w_b^T G_d w_b),
// w = y_hat - y, G_d[k1,k2] = sum_n bs[k1,n,d]*bs[k2,n,d].
// face cancels; EPS cross-term ~1e-6 relative -> dropped (validated r1/r2).
// Single fused kernel: 192 gram blocks atomicAdd partial Grams into G,
// 48 finalize blocks spin on a completion counter then do the q-forms.
#define NPTS     8192
#define KDIM     51
#define KPAD     64
#define CHUNKS   64
#define CHUNK_N  128
#define MULT     0.0025f
#define NGRAM    (3 * CHUNKS)   // 192
#define NFIN     48             // 3 d x 16 batch-groups of 16

typedef short short8  __attribute__((ext_vector_type(8)));
typedef float float4v __attribute__((ext_vector_type(4)));

__device__ __forceinline__ unsigned short f32_to_bf16(float f) {
  unsigned int u = __float_as_uint(f);
  unsigned int r = u + 0x7FFFu + ((u >> 16) & 1u);
  return (unsigned short)(r >> 16);
}

// ctrl[0] = gram-done counter, ctrl[1] = finalize-done counter,
// ctrl[2] = float accumulator (all memset to 0 on stream before launch).
__global__ __launch_bounds__(256) void pl_fused(
    const float* __restrict__ bs, const float* __restrict__ yh,
    const float* __restrict__ yv, float* __restrict__ out,
    unsigned* __restrict__ ctrl, float* __restrict__ G) {
  __shared__ __align__(16) char smem[20032];

  const int bx  = blockIdx.x;
  const int tid = threadIdx.x;

  if (bx < NGRAM) {
    // ---------------- gram block: (d, 128-pt chunk) partial via MFMA ------
    unsigned short* lds16 = (unsigned short*)smem;   // [KPAD][136] bf16
    unsigned int*   lds32 = (unsigned int*)smem;

    const int d  = bx / CHUNKS;
    const int n0 = (bx % CHUNKS) * CHUNK_N;

    // Stage bs[k][n0+2np..+1][d] -> lds16[k][2np..+1]; pair-packed writes:
    // banks (4k+np)%32 cover all 32, 2-way aliasing = free (m136).
    for (int u = tid; u < KPAD * (CHUNK_N / 2); u += 256) {
      int np = u & 63;
      int k  = u >> 6;
      float v0 = 0.0f, v1 = 0.0f;
      if (k < KDIM) {
        const float* p = bs + (size_t)k * (NPTS * 3) + (size_t)(n0 + 2 * np) * 3 + d;
        v0 = p[0];
        v1 = p[3];
      }
      lds32[k * 68 + np] = (unsigned int)f32_to_bf16(v0) |
                           ((unsigned int)f32_to_bf16(v1) << 16);
    }
    __syncthreads();

    const int wave  = tid >> 6;
    const int lane  = tid & 63;
    const int m16   = lane & 15;
    const int quad  = lane >> 4;
    const int rbase = (wave >> 1) * 32;   // each wave owns a 32x32 quadrant
    const int cbase = (wave & 1) * 32;

    float4v acc00 = {0.f,0.f,0.f,0.f}, acc01 = {0.f,0.f,0.f,0.f};
    float4v acc10 = {0.f,0.f,0.f,0.f}, acc11 = {0.f,0.f,0.f,0.f};

#pragma unroll
    for (int p0 = 0; p0 < CHUNK_N; p0 += 32) {
      const int po = p0 + quad * 8;
      short8 a0 = *(const short8*)&lds16[(rbase +      m16) * 136 + po];
      short8 a1 = *(const short8*)&lds16[(rbase + 16 + m16) * 136 + po];
      short8 b0 = *(const short8*)&lds16[(cbase +      m16) * 136 + po];
      short8 b1 = *(const short8*)&lds16[(cbase + 16 + m16) * 136 + po];
      acc00 = __builtin_amdgcn_mfma_f32_16x16x32_bf16(a0, b0, acc00, 0, 0, 0);
      acc01 = __builtin_amdgcn_mfma_f32_16x16x32_bf16(a0, b1, acc01, 0, 0, 0);
      acc10 = __builtin_amdgcn_mfma_f32_16x16x32_bf16(a1, b0, acc10, 0, 0, 0);
      acc11 = __builtin_amdgcn_mfma_f32_16x16x32_bf16(a1, b1, acc11, 0, 0, 0);
    }

    // AtomicAdd quadrant into G_d. G starts at poison 0xAA.. = -3.0e-13/entry
    // -> q-form error ~2e-10, negligible vs threshold 10.08. Padded rows/cols
    // (>=51) accumulate exact zeros and are never read by finalize.
    float* Gd = G + d * 4096;
#pragma unroll
    for (int r = 0; r < 4; ++r) {
      int row0 = rbase + quad * 4 + r;
      int col0 = cbase + m16;
      __hip_atomic_fetch_add(&Gd[row0 * 64 + col0],          acc00[r],
                             __ATOMIC_RELAXED, __HIP_MEMORY_SCOPE_AGENT);
      __hip_atomic_fetch_add(&Gd[row0 * 64 + col0 + 16],     acc01[r],
                             __ATOMIC_RELAXED, __HIP_MEMORY_SCOPE_AGENT);
      __hip_atomic_fetch_add(&Gd[(row0 + 16) * 64 + col0],   acc10[r],
                             __ATOMIC_RELAXED, __HIP_MEMORY_SCOPE_AGENT);
      __hip_atomic_fetch_add(&Gd[(row0 + 16) * 64 + col0 + 16], acc11[r],
                             __ATOMIC_RELAXED, __HIP_MEMORY_SCOPE_AGENT);
    }
    __threadfence();          // release my adds to device scope
    __syncthreads();          // all threads' adds+fences done
    if (tid == 0)
      __hip_atomic_fetch_add(&ctrl[0], 1u,
                             __ATOMIC_RELEASE, __HIP_MEMORY_SCOPE_AGENT);
  } else {
    // ---------------- finalize block: (d, 16-batch group) -----------------
    float* Gl  = (float*)smem;          // [64][65] bank-safe
    float* wl  = Gl + 64 * 65;          // [16][52]
    float* red = wl + 16 * 52;          // [16]

    const int idx = bx - NGRAM;
    const int d   = idx >> 4;
    const int b0  = (idx & 15) << 4;

    // Pre-stage w = y_hat - y while gram blocks run.
    for (int u = tid; u < 16 * KDIM; u += 256) {
      int bl = u / KDIM, k = u - bl * KDIM;
      int gi = (b0 + bl) * KDIM + k;
      wl[bl * 52 + k] = yh[gi] - yv[gi];
    }
    __syncthreads();

    // Spin until all 192 gram blocks signalled (all 240 blocks co-resident:
    // grid 240 <= 256 CUs, 20KB LDS -> no deadlock).
    if (tid == 0) {
      while (__hip_atomic_load(&ctrl[0], __ATOMIC_ACQUIRE,
                               __HIP_MEMORY_SCOPE_AGENT) < NGRAM)
        __builtin_amdgcn_s_sleep(4);
    }
    __syncthreads();
    __threadfence();

    // Read G_d with L1-bypassing atomic loads (G written via L2 atomics).
    for (int u = tid; u < 4096; u += 256)
      Gl[(u >> 6) * 65 + (u & 63)] =
          __hip_atomic_load(&G[d * 4096 + u], __ATOMIC_RELAXED,
                            __HIP_MEMORY_SCOPE_AGENT);
    __syncthreads();

    const int bl = tid >> 4;
    const int j  = tid & 15;
    float pq = 0.0f;
    for (int k1 = j; k1 < KDIM; k1 += 16) {
      float t = 0.0f;
      const float* gr = &Gl[k1 * 65];
      const float* wr = &wl[bl * 52];
#pragma unroll
      for (int k2 = 0; k2 < KDIM; ++k2) t = fmaf(gr[k2], wr[k2], t);
      pq = fmaf(wl[bl * 52 + k1], t, pq);
    }
    for (int off = 8; off; off >>= 1) pq += __shfl_down(pq, off, 16);
    if (j == 0) red[bl] = sqrtf(pq);
    __syncthreads();

    if (tid == 0) {
      float s = 0.0f;
#pragma unroll
      for (int i = 0; i < 16; ++i) s += red[i];
      float* accf = (float*)&ctrl[2];
      __hip_atomic_fetch_add(accf, s, __ATOMIC_RELAXED,
                             __HIP_MEMORY_SCOPE_AGENT);
      __threadfence();
      unsigned t2 = __hip_atomic_fetch_add(&ctrl[1], 1u, __ATOMIC_ACQ_REL,
                                           __HIP_MEMORY_SCOPE_AGENT);
      if (t2 == NFIN - 1) {
        float a = __hip_atomic_load(accf, __ATOMIC_RELAXED,
                                    __HIP_MEMORY_SCOPE_AGENT);
        out[0] = a * MULT;
      }
    }
  }
}

extern "C" void kernel_launch(void* const* d_in, const int* in_sizes, int n_in,
                              void* d_out, int out_size, void* d_ws, size_t ws_size,
                              hipStream_t stream) {
  const float* y_hat = (const float*)d_in[0];   // [256,51]
  const float* y     = (const float*)d_in[1];   // [256,51]
  // d_in[2] = face [8192,3] — cancels algebraically, unused
  const float* bs    = (const float*)d_in[3];   // [51,8192,3]
  float* out = (float*)d_out;

  unsigned* ctrl = (unsigned*)d_ws;                   // 3 dwords
  float*    G    = (float*)((char*)d_ws + 256);       // 3*4096 floats

  hipMemsetAsync(d_ws, 0, 12, stream);                // zero ctrl only
  pl_fused<<<NGRAM + NFIN, 256, 0, stream>>>(bs, y_hat, y, out, ctrl, G);
}

// Round 4
// 82.682 us; speedup vs baseline: 1.2511x; 1.2511x over previous
//
#include <hip/hip_runtime.h>
#include <math.h>

// B=256, K=51, N=8192. out = MULT * sum_{b,d} sqrt(w_b^T G_d w_b),
// w = y_hat - y, G_d[k1,k2] = sum_n bs[k1,n,d]*bs[k2,n,d].
// face cancels; EPS cross-term ~1e-6 relative -> dropped (validated r1-r3).
// R4: no spin/fences (R3's acquire-spin caused an L2-invalidate storm).
// Gram blocks now cover all 3 dims per n-chunk -> bs read is pure coalesced
// float4, consumed exactly once device-wide; de-interleave via ds_write_b16.
#define NPTS     8192
#define KDIM     51
#define KPAD     64
#define CHUNKS   64
#define CHUNK_N  128
#define MULT     0.0025f

typedef short short8  __attribute__((ext_vector_type(8)));
typedef float float4v __attribute__((ext_vector_type(4)));

__device__ __forceinline__ unsigned short f32_to_bf16(float f) {
  unsigned int u = __float_as_uint(f);
  unsigned int r = u + 0x7FFFu + ((u >> 16) & 1u);
  return (unsigned short)(r >> 16);
}

// ---------------------------------------------------------------------------
// Kernel 1: one block per 128-point chunk, all 3 dims.
// Stage: 51 rows x 96 float4 coalesced loads (16B-aligned: offsets are
// multiples of 384 dwords per row-chunk). Each float4 = dwords j..j+3 of the
// chunk row; dword j -> point p=j/3, dim dd=j%3 -> ds_write_b16 into
// conv16[dd][k][p], stride 136 bf16 (proven R2/R3 layout, ~2-way banks).
// MFMA: per wave one 32x32 quadrant as 2x2 16x16 tiles, looped over 3 dims.
// ---------------------------------------------------------------------------
__global__ __launch_bounds__(256) void pl_gram(
    const float* __restrict__ bs, float* __restrict__ partial) {
  __shared__ unsigned short conv16[3 * KPAD * 136];   // 52224 B

  const int bx  = blockIdx.x;      // n-chunk
  const int tid = threadIdx.x;

  // Zero pad rows k=51..63 (so G rows/cols >=51 are exact zeros, never NaN).
  unsigned int* conv32 = (unsigned int*)conv16;
  for (int u = tid; u < 3 * 13 * 68; u += 256) {
    int dd  = u / (13 * 68);
    int rem = u - dd * (13 * 68);
    int r   = rem / 68;
    int w   = rem - r * 68;
    conv32[(dd * KPAD + 51 + r) * 68 + w] = 0u;
  }

  // Stage + convert: 51 rows x 96 float4 per block (bs row k, dwords
  // [k*24576 + bx*384, +384)). Fully coalesced, ~19 independent loads/thread.
  const float4* src = (const float4*)bs;
  for (int u = tid; u < KDIM * 96; u += 256) {
    int k = u / 96;
    int c = u - k * 96;
    float4 v = src[(size_t)k * 6144 + bx * 96 + c];
    float f[4] = {v.x, v.y, v.z, v.w};
    int j0 = 4 * c;
#pragma unroll
    for (int e = 0; e < 4; ++e) {
      int j  = j0 + e;          // 0..383
      int p  = j / 3;           // point within chunk
      int dd = j - 3 * p;       // dim
      conv16[(dd * KPAD + k) * 136 + p] = f32_to_bf16(f[e]);
    }
  }
  __syncthreads();

  const int wave  = tid >> 6;
  const int lane  = tid & 63;
  const int m16   = lane & 15;
  const int quad  = lane >> 4;
  const int rbase = (wave >> 1) * 32;   // wave's 32x32 quadrant
  const int cbase = (wave & 1) * 32;

  for (int dd = 0; dd < 3; ++dd) {
    const unsigned short* base = conv16 + dd * KPAD * 136;
    float4v acc00 = {0.f,0.f,0.f,0.f}, acc01 = {0.f,0.f,0.f,0.f};
    float4v acc10 = {0.f,0.f,0.f,0.f}, acc11 = {0.f,0.f,0.f,0.f};
#pragma unroll
    for (int p0 = 0; p0 < CHUNK_N; p0 += 32) {
      const int po = p0 + quad * 8;
      short8 a0 = *(const short8*)&base[(rbase +      m16) * 136 + po];
      short8 a1 = *(const short8*)&base[(rbase + 16 + m16) * 136 + po];
      short8 b0 = *(const short8*)&base[(cbase +      m16) * 136 + po];
      short8 b1 = *(const short8*)&base[(cbase + 16 + m16) * 136 + po];
      acc00 = __builtin_amdgcn_mfma_f32_16x16x32_bf16(a0, b0, acc00, 0, 0, 0);
      acc01 = __builtin_amdgcn_mfma_f32_16x16x32_bf16(a0, b1, acc01, 0, 0, 0);
      acc10 = __builtin_amdgcn_mfma_f32_16x16x32_bf16(a1, b0, acc10, 0, 0, 0);
      acc11 = __builtin_amdgcn_mfma_f32_16x16x32_bf16(a1, b1, acc11, 0, 0, 0);
    }
    // Natural [row][col] partial, layout partial[d][chunk][4096].
    float* pout = partial + ((size_t)dd * CHUNKS + bx) * 4096;
#pragma unroll
    for (int r = 0; r < 4; ++r) {
      int row0 = rbase + quad * 4 + r;
      int col0 = cbase + m16;
      pout[row0 * 64 + col0]               = acc00[r];
      pout[row0 * 64 + (col0 + 16)]        = acc01[r];
      pout[(row0 + 16) * 64 + col0]        = acc10[r];
      pout[(row0 + 16) * 64 + (col0 + 16)] = acc11[r];
    }
  }
}

// ---------------------------------------------------------------------------
// Kernel 2: reduce 64 chunk partials -> G[3][4096]; zero d_out for kernel 3.
// ---------------------------------------------------------------------------
__global__ __launch_bounds__(256) void pl_reduce_gram(
    const float* __restrict__ partial, float* __restrict__ G,
    float* __restrict__ out) {
  int e = blockIdx.x * 256 + threadIdx.x;   // [0, 3*4096)
  int d = e >> 12, el = e & 4095;
  float s0 = 0.f, s1 = 0.f, s2 = 0.f, s3 = 0.f;
  const float* p = partial + (size_t)d * CHUNKS * 4096 + el;
#pragma unroll
  for (int c = 0; c < CHUNKS; c += 4) {     // 4 independent chains for MLP
    s0 += p[(size_t)(c + 0) * 4096];
    s1 += p[(size_t)(c + 1) * 4096];
    s2 += p[(size_t)(c + 2) * 4096];
    s3 += p[(size_t)(c + 3) * 4096];
  }
  G[e] = (s0 + s1) + (s2 + s3);
  if (e == 0) out[0] = 0.0f;
}

// ---------------------------------------------------------------------------
// Kernel 3: q[b,d] = w_b^T G_d w_b, out += MULT * sum sqrt(q).
// 48 blocks = 3 d x 16 groups of 16 batch rows; 256 thr = (row, 16-j strip).
// ---------------------------------------------------------------------------
__global__ __launch_bounds__(256) void pl_finalize(
    const float* __restrict__ G, const float* __restrict__ yh,
    const float* __restrict__ yv, float* __restrict__ out) {
  __shared__ float Gl[64 * 65];   // stride 65: bank-safe rows
  __shared__ float wl[16 * 52];
  __shared__ float red2[16];

  const int bx  = blockIdx.x;
  const int d   = bx >> 4;
  const int b0  = (bx & 15) << 4;
  const int tid = threadIdx.x;

  for (int idx = tid; idx < 4096; idx += 256)
    Gl[(idx >> 6) * 65 + (idx & 63)] = G[d * 4096 + idx];
  for (int idx = tid; idx < 16 * KDIM; idx += 256) {
    int bl = idx / KDIM, k = idx - bl * KDIM;
    int gi = (b0 + bl) * KDIM + k;
    wl[bl * 52 + k] = yh[gi] - yv[gi];
  }
  __syncthreads();

  const int bl = tid >> 4;
  const int j  = tid & 15;
  float pq = 0.0f;
  for (int k1 = j; k1 < KDIM; k1 += 16) {
    float t = 0.0f;
    const float* gr = &Gl[k1 * 65];
    const float* wr = &wl[bl * 52];
#pragma unroll
    for (int k2 = 0; k2 < KDIM; ++k2) t = fmaf(gr[k2], wr[k2], t);
    pq = fmaf(wl[bl * 52 + k1], t, pq);
  }
  for (int off = 8; off; off >>= 1) pq += __shfl_down(pq, off, 16);
  if (j == 0) red2[bl] = sqrtf(pq);
  __syncthreads();
  if (tid == 0) {
    float s = 0.0f;
#pragma unroll
    for (int i = 0; i < 16; ++i) s += red2[i];
    atomicAdd(out, s * MULT);
  }
}

extern "C" void kernel_launch(void* const* d_in, const int* in_sizes, int n_in,
                              void* d_out, int out_size, void* d_ws, size_t ws_size,
                              hipStream_t stream) {
  const float* y_hat = (const float*)d_in[0];   // [256,51]
  const float* y     = (const float*)d_in[1];   // [256,51]
  // d_in[2] = face [8192,3] — cancels algebraically, unused
  const float* bs    = (const float*)d_in[3];   // [51,8192,3]
  float* out = (float*)d_out;

  float* partial = (float*)d_ws;                          // 3*64*4096 floats
  float* G       = partial + (size_t)3 * CHUNKS * 4096;   // 3*4096 floats

  pl_gram<<<CHUNKS, 256, 0, stream>>>(bs, partial);
  pl_reduce_gram<<<48, 256, 0, stream>>>(partial, G, out);
  pl_finalize<<<48, 256, 0, stream>>>(G, y_hat, y, out);
}